// Round 7
// baseline (443.414 us; speedup 1.0000x reference)
//
#include <hip/hip_runtime.h>
#include <math.h>

#define HH 16
#define SS 2048
#define DD 128
#define NROWS (HH * SS)            // 32768
#define OUTSZ (HH * SS * DD)       // 4194304 elems per tensor

typedef __attribute__((ext_vector_type(8))) short bf16x8;
typedef __attribute__((ext_vector_type(4))) float f32x4;
typedef __attribute__((ext_vector_type(8))) unsigned short u16x8;

#define MFMA16(a, b, c) __builtin_amdgcn_mfma_f32_16x16x32_bf16(a, b, c, 0, 0, 0)

__device__ __forceinline__ unsigned short f2bf(float f) {
    unsigned u = __float_as_uint(f);
    return (unsigned short)((u + 0x7FFFu + ((u >> 16) & 1u)) >> 16);   // RNE
}
__device__ __forceinline__ bf16x8 negf(bf16x8 a) {
    bf16x8 r;
#pragma unroll
    for (int j = 0; j < 8; ++j) r[j] = (short)(a[j] ^ (short)0x8000);
    return r;
}

struct ClinPtrs {
    const float* xr; const float* xi;
    const float* gr; const float* gi;     // GATE only
    const float* wr; const float* wi;
    const float* br; const float* bi;
    const float* per; const float* pei;   // may be null
    void* yr; void* yi;
    int outbf;                            // 1: bf16 out, 0: fp32 out
};

// ---------------------------------------------------------------------------
// MFMA complex linear. 512 thr = 8 waves, NS slabs of 16 rows per wave
// (128*NS rows/block), full 128 cols. grid (NROWS/(128*NS), nproj).
// R6 restructure, from the observation that clin is latency-bound at
// 1 block/CU (VGPR ~200 -> 2 waves/SIMD -> one 512-thr block):
//  - NS=2 for the 4-projection pass: grid (128,4)=512 blocks -> 2 rounds
//    per CU instead of 4; W staged 128x per proj instead of 256x; W LDS
//    fragments read once per (dk,nt) feed BOTH slabs (halved LDS reads).
//  - A-row globals prefetched into registers BEFORE the W-stage so HBM
//    latency hides under staging work (T14 issue-early).
// GATE: x = (xr,xi) (*) (gr,gi) complex product at fragment build.
// In-place final proj safe: all of a wave's reads (prefetch, top of
// kernel) precede its epilogue stores; rows are wave/block-disjoint.
// ---------------------------------------------------------------------------
template <int NS, bool GATE>
__global__ __launch_bounds__(512, 2)
void clin_mfma(ClinPtrs P0, ClinPtrs P1, ClinPtrs P2, ClinPtrs P3) {
    __shared__ unsigned short wsh[2][DD][136];   // 69632 B

    const int py = blockIdx.y;
    const ClinPtrs P = (py == 0) ? P0 : (py == 1) ? P1 : (py == 2) ? P2 : P3;

    const int t = threadIdx.x;
    const int w = t >> 6, lane = t & 63;
    const int lm = lane & 15, quad = lane >> 4;
    const long m0 = (long)blockIdx.x * (128 * NS) + w * (16 * NS);

    // ---- prefetch raw A rows (and gate rows) BEFORE W staging ----
    float4 xa0[NS][4], xa1[NS][4], xb0[NS][4], xb1[NS][4];
#pragma unroll
    for (int s = 0; s < NS; ++s) {
        const long rbase = (m0 + s * 16 + lm) * DD;
#pragma unroll
        for (int dk = 0; dk < 4; ++dk) {
            const long o = rbase + dk * 32 + quad * 8;
            xa0[s][dk] = *(const float4*)(P.xr + o);
            xa1[s][dk] = *(const float4*)(P.xr + o + 4);
            xb0[s][dk] = *(const float4*)(P.xi + o);
            xb1[s][dk] = *(const float4*)(P.xi + o + 4);
        }
    }
    float4 ga0[NS][4], ga1[NS][4], gb0[NS][4], gb1[NS][4];
    if (GATE) {
#pragma unroll
        for (int s = 0; s < NS; ++s) {
            const long rbase = (m0 + s * 16 + lm) * DD;
#pragma unroll
            for (int dk = 0; dk < 4; ++dk) {
                const long o = rbase + dk * 32 + quad * 8;
                ga0[s][dk] = *(const float4*)(P.gr + o);
                ga1[s][dk] = *(const float4*)(P.gr + o + 4);
                gb0[s][dk] = *(const float4*)(P.gi + o);
                gb1[s][dk] = *(const float4*)(P.gi + o + 4);
            }
        }
    }

    // ---- stage W fp32->bf16 (4096 groups of 8) ----
#pragma unroll
    for (int u = 0; u < 8; ++u) {
        const int f = t + 512 * u;
        const int c = f >> 11;
        const int rem = f & 2047;
        const int row = rem >> 4;
        const int g8 = (rem & 15) * 8;
        const float* src = (c ? P.wi : P.wr) + (long)row * DD + g8;
        const float4 a = *(const float4*)src;
        const float4 b = *(const float4*)(src + 4);
        unsigned short tmp[8] = {f2bf(a.x), f2bf(a.y), f2bf(a.z), f2bf(a.w),
                                 f2bf(b.x), f2bf(b.y), f2bf(b.z), f2bf(b.w)};
        *(u16x8*)&wsh[c][row][g8] = *(u16x8*)tmp;
    }

    // ---- build A fragments from prefetched rows ----
    bf16x8 xrf[NS][4], xif[NS][4];
#pragma unroll
    for (int s = 0; s < NS; ++s)
#pragma unroll
        for (int dk = 0; dk < 4; ++dk) {
            float fr[8] = {xa0[s][dk].x, xa0[s][dk].y, xa0[s][dk].z, xa0[s][dk].w,
                           xa1[s][dk].x, xa1[s][dk].y, xa1[s][dk].z, xa1[s][dk].w};
            float fi[8] = {xb0[s][dk].x, xb0[s][dk].y, xb0[s][dk].z, xb0[s][dk].w,
                           xb1[s][dk].x, xb1[s][dk].y, xb1[s][dk].z, xb1[s][dk].w};
            if (GATE) {
                const float ur[8] = {ga0[s][dk].x, ga0[s][dk].y, ga0[s][dk].z, ga0[s][dk].w,
                                     ga1[s][dk].x, ga1[s][dk].y, ga1[s][dk].z, ga1[s][dk].w};
                const float ui[8] = {gb0[s][dk].x, gb0[s][dk].y, gb0[s][dk].z, gb0[s][dk].w,
                                     gb1[s][dk].x, gb1[s][dk].y, gb1[s][dk].z, gb1[s][dk].w};
#pragma unroll
                for (int j = 0; j < 8; ++j) {
                    const float pr = fr[j] * ur[j] - fi[j] * ui[j];
                    const float pi = fr[j] * ui[j] + fi[j] * ur[j];
                    fr[j] = pr; fi[j] = pi;
                }
            }
#pragma unroll
            for (int j = 0; j < 8; ++j) {
                xrf[s][dk][j] = (short)f2bf(fr[j]);
                xif[s][dk][j] = (short)f2bf(fi[j]);
            }
        }

    f32x4 Or[NS][8], Oi[NS][8];
    const f32x4 z = {0.f, 0.f, 0.f, 0.f};
#pragma unroll
    for (int s = 0; s < NS; ++s)
#pragma unroll
        for (int nt = 0; nt < 8; ++nt) { Or[s][nt] = z; Oi[s][nt] = z; }

    __syncthreads();

    // ---- MFMA: W fragment read once per (dk,nt), feeds all NS slabs ----
#pragma unroll
    for (int dk = 0; dk < 4; ++dk) {
        const int off = dk * 32 + quad * 8;
        bf16x8 nxi[NS];
#pragma unroll
        for (int s = 0; s < NS; ++s) nxi[s] = negf(xif[s][dk]);
#pragma unroll
        for (int nt = 0; nt < 8; ++nt) {
            const bf16x8 wrf = *(bf16x8*)&wsh[0][nt * 16 + lm][off];
            const bf16x8 wif = *(bf16x8*)&wsh[1][nt * 16 + lm][off];
#pragma unroll
            for (int s = 0; s < NS; ++s) {
                Or[s][nt] = MFMA16(xrf[s][dk], wrf, Or[s][nt]);
                Or[s][nt] = MFMA16(nxi[s],     wif, Or[s][nt]);
                Oi[s][nt] = MFMA16(xrf[s][dk], wif, Oi[s][nt]);
                Oi[s][nt] = MFMA16(xif[s][dk], wrf, Oi[s][nt]);
            }
        }
    }

    // ---- epilogue: C layout row = quad*4+reg, col = nt*16 + lm ----
#pragma unroll
    for (int s = 0; s < NS; ++s)
#pragma unroll
        for (int nt = 0; nt < 8; ++nt) {
            const int c = nt * 16 + lm;
            const float bra = P.br[c], bia = P.bi[c];
#pragma unroll
            for (int reg = 0; reg < 4; ++reg) {
                const long R = m0 + s * 16 + quad * 4 + reg;
                float vr = Or[s][nt][reg] + bra;
                float vi = Oi[s][nt][reg] + bia;
                if (P.per != nullptr) {
                    vr += P.per[R * DD + c];
                    vi += P.pei[R * DD + c];
                }
                if (P.outbf) {
                    ((unsigned short*)P.yr)[R * DD + c] = f2bf(vr);
                    ((unsigned short*)P.yi)[R * DD + c] = f2bf(vi);
                } else {
                    ((float*)P.yr)[R * DD + c] = vr;
                    ((float*)P.yi)[R * DD + c] = vi;
                }
            }
        }
}

// ---------------------------------------------------------------------------
// MFMA flash attention, complex-magnitude scores. bf16 q,k,v inputs.
// EXACT R3 configuration (130.7 us, best measured): 512 thr = 8 waves,
// 16 q-rows/wave, Bq=128, Bk=32, grid 256 XCD-swizzled, double-buffered
// K/V with register prefetch, fixed-offset softmax (no max tracking).
// R4 (fat waves, 1/SIMD) and R5 (2 small blocks) both regressed -> this
// structure is the bracketed local optimum for the attn kernel.
// ---------------------------------------------------------------------------
__global__ __launch_bounds__(512, 2)
void attn_mfma(const unsigned short* __restrict__ qr, const unsigned short* __restrict__ qi,
               const unsigned short* __restrict__ kr, const unsigned short* __restrict__ ki,
               const unsigned short* __restrict__ vr, const unsigned short* __restrict__ vi,
               float* __restrict__ out_r, float* __restrict__ out_i) {
    __shared__ unsigned short ks[2][2][32][136];   // 34816 B  [buf][comp][k][d]
    __shared__ unsigned short vt[2][2][DD][40];    // 40960 B  [buf][comp][d][k]
    __shared__ unsigned short ps[128][40];         // 10240 B  (P, bf16)

    const int t = threadIdx.x;
    const int w = t >> 6, lane = t & 63;
    const int lm = lane & 15, quad = lane >> 4;

    // XCD swizzle: xcd = bid%8; head h = xcd + 8*(rr>>4); qt = rr&15
    const int bid = blockIdx.x;
    const int xcd = bid & 7;
    const int rr = bid >> 3;          // 0..31
    const int qt = rr & 15;
    const int h  = xcd + 8 * (rr >> 4);
    const long hbase = (long)h * SS * DD;
    const int q0 = qt * 128;
    const float scale = 0.08838834764831845f;   // 128^-0.5

    // ---- staging thread->element maps (constant per thread) ----
    int kC[2], kR[2], kG[2];
    const unsigned short* kp[2];
#pragma unroll
    for (int u = 0; u < 2; ++u) {
        const int f = t + 512 * u;
        kC[u] = f >> 9;                 // 0: kr, 1: ki
        kR[u] = (f & 511) >> 4;         // k row 0..31
        kG[u] = (f & 15) * 8;           // d group
        kp[u] = (kC[u] ? ki : kr) + hbase + (long)kR[u] * DD + kG[u];
    }
    const int vC = t >> 8;              // 0: vr, 1: vi
    const int vS2 = (t & 15) * 2;       // k pair 0..30
    const int vD8 = ((t >> 4) & 15) * 8;
    const unsigned short* vp = (vC ? vi : vr) + hbase + (long)vS2 * DD + vD8;

    u16x8 kA0, kA1, vA0, vA1;           // in-flight staging registers
    // ---- issue tile-0 loads ----
    kA0 = *(const u16x8*)(kp[0]);
    kA1 = *(const u16x8*)(kp[1]);
    vA0 = *(const u16x8*)(vp);
    vA1 = *(const u16x8*)(vp + DD);

    // ---- resident Q fragments (A layout), 16 rows per wave ----
    bf16x8 qrf[4], qif[4];
    {
        const long rb = hbase + (long)(q0 + w * 16 + lm) * DD;
#pragma unroll
        for (int dk = 0; dk < 4; ++dk) {
            qrf[dk] = *(const bf16x8*)(qr + rb + dk * 32 + quad * 8);
            qif[dk] = *(const bf16x8*)(qi + rb + dk * 32 + quad * 8);
        }
    }

    f32x4 Or[8], Oi[8];
    const f32x4 z = {0.f, 0.f, 0.f, 0.f};
#pragma unroll
    for (int nt = 0; nt < 8; ++nt) { Or[nt] = z; Oi[nt] = z; }
    float l_st[4] = {0.f, 0.f, 0.f, 0.f};

    // ---- write tile 0 into buf 0 ----
#pragma unroll
    for (int u = 0; u < 2; ++u)
        *(u16x8*)&ks[0][kC[u]][kR[u]][kG[u]] = (u ? kA1 : kA0);
#pragma unroll
    for (int j = 0; j < 8; ++j) {
        const unsigned val = (unsigned)(unsigned short)vA0[j] |
                             ((unsigned)(unsigned short)vA1[j] << 16);
        *(unsigned*)&vt[0][vC][vD8 + j][vS2] = val;
    }
    __syncthreads();

    for (int kt = 0; kt < SS / 32; ++kt) {
        const int b = kt & 1;
        // ---- issue next tile's global loads (latency hides under compute) ----
        if (kt + 1 < SS / 32) {
            const long koff = (long)(kt + 1) * 32 * DD;
            kA0 = *(const u16x8*)(kp[0] + koff);
            kA1 = *(const u16x8*)(kp[1] + koff);
            vA0 = *(const u16x8*)(vp + koff);
            vA1 = *(const u16x8*)(vp + koff + DD);
        }

        // ---- scores: two 16x16 tiles (k cols 0-15, 16-31) ----
        f32x4 sr0 = z, sr1 = z, si0 = z, si1 = z;
#pragma unroll
        for (int dk = 0; dk < 4; ++dk) {
            const int off = dk * 32 + quad * 8;
            const bf16x8 kr0 = *(bf16x8*)&ks[b][0][lm][off];
            const bf16x8 ki0 = *(bf16x8*)&ks[b][1][lm][off];
            const bf16x8 kr1 = *(bf16x8*)&ks[b][0][16 + lm][off];
            const bf16x8 ki1 = *(bf16x8*)&ks[b][1][16 + lm][off];
            const bf16x8 nq = negf(qrf[dk]);
            sr0 = MFMA16(qrf[dk], kr0, sr0);  sr0 = MFMA16(qif[dk], ki0, sr0);
            si0 = MFMA16(qif[dk], kr0, si0);  si0 = MFMA16(nq, ki0, si0);
            sr1 = MFMA16(qrf[dk], kr1, sr1);  sr1 = MFMA16(qif[dk], ki1, sr1);
            si1 = MFMA16(qif[dk], kr1, si1);  si1 = MFMA16(nq, ki1, si1);
        }

        // ---- fixed-offset softmax: p = exp(s), no max tracking ----
#pragma unroll
        for (int reg = 0; reg < 4; ++reg) {
            const float s0 = __builtin_amdgcn_sqrtf(
                fmaf(sr0[reg], sr0[reg], fmaf(si0[reg], si0[reg], 1e-8f))) * scale;
            const float s1 = __builtin_amdgcn_sqrtf(
                fmaf(sr1[reg], sr1[reg], fmaf(si1[reg], si1[reg], 1e-8f))) * scale;
            const float p0 = __expf(s0);
            const float p1 = __expf(s1);
            l_st[reg] += p0 + p1;
            ps[w * 16 + quad * 4 + reg][lm]      = f2bf(p0);
            ps[w * 16 + quad * 4 + reg][16 + lm] = f2bf(p1);
        }

        // ---- PV: P (A layout via LDS, intra-wave) x V^T tiles ----
        const bf16x8 pf = *(bf16x8*)&ps[w * 16 + lm][quad * 8];
#pragma unroll
        for (int nt = 0; nt < 8; ++nt) {
            const bf16x8 vrf = *(bf16x8*)&vt[b][0][nt * 16 + lm][quad * 8];
            const bf16x8 vif = *(bf16x8*)&vt[b][1][nt * 16 + lm][quad * 8];
            Or[nt] = MFMA16(pf, vrf, Or[nt]);
            Oi[nt] = MFMA16(pf, vif, Oi[nt]);
        }

        // ---- write prefetched tile into other buffer ----
        if (kt + 1 < SS / 32) {
            __syncthreads();   // all waves done reading buf b^1 (iter kt-1)
#pragma unroll
            for (int u = 0; u < 2; ++u)
                *(u16x8*)&ks[b ^ 1][kC[u]][kR[u]][kG[u]] = (u ? kA1 : kA0);
#pragma unroll
            for (int j = 0; j < 8; ++j) {
                const unsigned val = (unsigned)(unsigned short)vA0[j] |
                                     ((unsigned)(unsigned short)vA1[j] << 16);
                *(unsigned*)&vt[b ^ 1][vC][vD8 + j][vS2] = val;
            }
            __syncthreads();   // writes visible before iter kt+1 reads
        }
    }

    // ---- finalize: reduce l across 16-lane group, scale, store ----
    float linv[4];
#pragma unroll
    for (int reg = 0; reg < 4; ++reg) {
        float l = l_st[reg];
#pragma unroll
        for (int off = 1; off < 16; off <<= 1) l += __shfl_xor(l, off);
        linv[reg] = 1.f / l;
    }
    const long ob = hbase + (long)(q0 + w * 16) * DD;
#pragma unroll
    for (int nt = 0; nt < 8; ++nt) {
        const int c = nt * 16 + lm;
#pragma unroll
        for (int reg = 0; reg < 4; ++reg) {
            const long R = ob + (long)(quad * 4 + reg) * DD + c;
            out_r[R] = Or[nt][reg] * linv[reg];
            out_i[R] = Oi[nt][reg] * linv[reg];
        }
    }
}

// ---------------------------------------------------------------------------
extern "C" void kernel_launch(void* const* d_in, const int* in_sizes, int n_in,
                              void* d_out, int out_size, void* d_ws, size_t ws_size,
                              hipStream_t stream) {
    const float* q_r    = (const float*)d_in[0];
    const float* q_i    = (const float*)d_in[1];
    const float* k_r    = (const float*)d_in[2];
    const float* k_i    = (const float*)d_in[3];
    const float* v_r    = (const float*)d_in[4];
    const float* v_i    = (const float*)d_in[5];
    const float* pe_q_r = (const float*)d_in[6];
    const float* pe_q_i = (const float*)d_in[7];
    const float* pe_k_r = (const float*)d_in[8];
    const float* pe_k_i = (const float*)d_in[9];
    const float* qw_r = (const float*)d_in[10];
    const float* qw_i = (const float*)d_in[11];
    const float* qb_r = (const float*)d_in[12];
    const float* qb_i = (const float*)d_in[13];
    const float* kw_r = (const float*)d_in[14];
    const float* kw_i = (const float*)d_in[15];
    const float* kb_r = (const float*)d_in[16];
    const float* kb_i = (const float*)d_in[17];
    const float* vw_r = (const float*)d_in[18];
    const float* vw_i = (const float*)d_in[19];
    const float* vb_r = (const float*)d_in[20];
    const float* vb_i = (const float*)d_in[21];
    const float* gw_r = (const float*)d_in[22];
    const float* gw_i = (const float*)d_in[23];
    const float* gb_r = (const float*)d_in[24];
    const float* gb_i = (const float*)d_in[25];
    const float* ow_r = (const float*)d_in[26];
    const float* ow_i = (const float*)d_in[27];
    const float* ob_r = (const float*)d_in[28];
    const float* ob_i = (const float*)d_in[29];

    float* out_r = (float*)d_out;              // attn a_r temp, then final out_r
    float* out_i = out_r + (long)OUTSZ;
    float* g_r   = out_r + 2L * OUTSZ;
    float* g_i   = out_r + 3L * OUTSZ;

    unsigned short* ws = (unsigned short*)d_ws; // 6 x 8 MiB bf16
    unsigned short* pqr = ws + 0L * OUTSZ;
    unsigned short* pqi = ws + 1L * OUTSZ;
    unsigned short* pkr = ws + 2L * OUTSZ;
    unsigned short* pki = ws + 3L * OUTSZ;
    unsigned short* pvr = ws + 4L * OUTSZ;
    unsigned short* pvi = ws + 5L * OUTSZ;

    const dim3 blk(512);

    ClinPtrs P0 = {q_r, q_i, nullptr, nullptr, qw_r, qw_i, qb_r, qb_i,
                   pe_q_r, pe_q_i, pqr, pqi, 1};
    ClinPtrs P1 = {k_r, k_i, nullptr, nullptr, kw_r, kw_i, kb_r, kb_i,
                   pe_k_r, pe_k_i, pkr, pki, 1};
    ClinPtrs P2 = {v_r, v_i, nullptr, nullptr, vw_r, vw_i, vb_r, vb_i,
                   nullptr, nullptr, pvr, pvi, 1};
    ClinPtrs P3 = {q_r, q_i, nullptr, nullptr, gw_r, gw_i, gb_r, gb_i,
                   nullptr, nullptr, g_r, g_i, 0};

    // 4 projections, 256 rows/block (2 slabs/wave): grid (128,4) = 512
    // blocks = exactly 2 rounds at 1 block/CU; W staged half as often.
    clin_mfma<2, false><<<dim3(NROWS / 256, 4), blk, 0, stream>>>(P0, P1, P2, P3);

    // flash attention -> a_r, a_i parked in d_out slots 0,1 (exact R3)
    attn_mfma<<<dim3((SS / 128) * HH), blk, 0, stream>>>(
        pqr, pqi, pkr, pki, pvr, pvi, out_r, out_i);

    // gate + o-projection, in-place over d_out slots 0,1 (row-disjoint)
    ClinPtrs PF = {g_r, g_i, out_r, out_i, ow_r, ow_i, ob_r, ob_i,
                   nullptr, nullptr, out_r, out_i, 0};
    clin_mfma<1, true><<<dim3(NROWS / 128, 1), blk, 0, stream>>>(PF, PF, PF, PF);
}